// Round 1
// 120.177 us; speedup vs baseline: 1.0145x; 1.0145x over previous
//
#include <hip/hip_runtime.h>

#define Bsz 64
#define Nn  256
#define Ee  20   // atom embedding dim
#define Dd  25   // gaussian centers
#define NBLK 2048  // 2048 blocks x 4 waves x 2 rows = 16384 (b,i) rows

using short8  = __attribute__((ext_vector_type(8))) short;  // 8 bf16 (4 VGPRs)
using floatx4 = __attribute__((ext_vector_type(4))) float;  // 4 fp32 acc

#if __has_builtin(__builtin_amdgcn_exp2f)
#define EXP2F(x) __builtin_amdgcn_exp2f(x)
#else
#define EXP2F(x) __expf(0.6931471805599453f * (x))
#endif
#if __has_builtin(__builtin_amdgcn_rcpf)
#define RCPF(x) __builtin_amdgcn_rcpf(x)
#else
#define RCPF(x) (1.0f / (x))
#endif

__device__ __forceinline__ short f2bf(float x) {            // RNE fp32->bf16
    unsigned u = __float_as_uint(x);
    unsigned r = (u + 0x7FFFu + ((u >> 16) & 1u)) >> 16;
    return (short)r;
}
__device__ __forceinline__ float bf2f(short h) {
    return __uint_as_float(((unsigned)(unsigned short)h) << 16);
}
__device__ __forceinline__ float tanhfast(float x) {
    float e = __expf(2.0f * x);
    return 1.0f - 2.0f / (e + 1.0f);
}
// pack two fp32 -> two bf16 (RTNA; validated R6-R8)
__device__ __forceinline__ unsigned packbf(float a, float b) {
#if __has_builtin(__builtin_amdgcn_perm)
    return __builtin_amdgcn_perm(__float_as_uint(b) + 0x8000u,
                                 __float_as_uint(a) + 0x8000u, 0x07060302u);
#else
    unsigned ua = (__float_as_uint(a) + 0x8000u) >> 16;
    unsigned ub = (__float_as_uint(b) + 0x8000u) & 0xFFFF0000u;
    return ua | ub;
#endif
}

// Main kernel. Each wave owns 2 rows (b,i0),(b,i0+1); 4 waves/block share b.
// d-distribution: direct broadcast loads (lane reads j = 16t + c16).
// Tail channels (o=16..19): DPP-compacted so each lane exponentiates exactly
// one VALID tail element per (row,iter); per-lane tail channel = 16+(lane&3).
__global__ __launch_bounds__(256, 4) void dtnn_main(
    const int*   __restrict__ z,     // [B,N]
    const float* __restrict__ dist,  // [B,N,N]
    const float* __restrict__ emb,   // [N,E]
    const float* __restrict__ Vw,    // [E,45]
    const float* __restrict__ Vb,    // [E]
    const float* __restrict__ W1,    // [10,E]
    const float* __restrict__ W2,    // [1,10]
    float*       __restrict__ part)  // [NBLK]
{
    const int tid  = threadIdx.x;
    const int lane = tid & 63;
    const int wave = tid >> 6;
    const int blk  = blockIdx.x;
    const int b    = blk >> 5;                       // 32 blocks per batch
    const int i0   = ((blk & 31) << 3) | (wave << 1);// rows i0, i0+1

    const int c16  = lane & 15;
    const int quad = lane >> 4;
    const int k0   = quad * 8;
    const float Kc = 2.8853900817779268f;            // 2*log2(e)
    const float T04 = 1.1541560327111707f;           // 0.4*Kc

    // per-lane broadcast pointer: lane reads dist[b][i0(+1)][16*t + c16]
    const float* dpl = dist + ((size_t)b * Nn + i0) * Nn + c16;

    const int zi0 = z[b * Nn + i0];
    const int zi1 = z[b * Nn + i0 + 1];
    const int zu0 = __builtin_amdgcn_readfirstlane(zi0);  // wave-uniform
    const int zu1 = __builtin_amdgcn_readfirstlane(zi1);
    const float m0 = (zu0 != 0) ? 1.0f : 0.0f;
    const float m1 = (zu1 != 0) ? 1.0f : 0.0f;

    // Gaussian step constants c_jj = e^{-0.08 jj^2}, folded into the weights.
    const float cj[8] = {1.0f, 0.9231163463866358f, 0.7261490370736909f,
                         0.48675225595997157f, 0.2780373004531941f,
                         0.1353352832366127f, 0.05613476283303940f,
                         0.019841459768337877f};

    // weight fragments (divergent gathers; L1-hot) + per-row bias
    short8 whiK[2], wloK[2];
    floatx4 bias0[2], bias1[2];
    #pragma unroll
    for (int nt = 0; nt < 2; ++nt) {
        const int o = nt * 16 + c16;
        const bool valid = (o < Ee);
        const int oc = valid ? o : 0;                 // clamp vs OOB speculation
        #pragma unroll
        for (int jj = 0; jj < 8; ++jj) {
            const int k = k0 + jj;
            const float v = (valid && k < Dd)
                          ? Kc * cj[jj] * Vw[oc * 45 + 20 + k] : 0.0f;
            const short h = f2bf(v);
            whiK[nt][jj] = h;
            wloK[nt][jj] = f2bf(v - bf2f(h));
        }
        // A[o] = Kc*(Vb[o] + m * Vw[o,:20].emb[z])
        float dot0 = 0.0f, dot1 = 0.0f;
        #pragma unroll
        for (int f = 0; f < Ee; ++f) {
            const float w = valid ? Vw[oc * 45 + f] : 0.0f;
            dot0 = fmaf(w, emb[zu0 * Ee + f], dot0);   // emb: s_loads (uniform)
            dot1 = fmaf(w, emb[zu1 * Ee + f], dot1);
        }
        const float vb = valid ? Vb[oc] : 0.0f;
        const float A0 = Kc * (vb + m0 * dot0);
        const float A1 = Kc * (vb + m1 * dot1);
        bias0[nt] = (floatx4){A0, A0, A0, A0};
        bias1[nt] = (floatx4){A1, A1, A1, A1};
    }

    // ---- main loop: 16 j-tiles x 2 rows; sum tanh = 256 - 2*sum sigma
    const float mu0 = 0.2f * (float)k0;
    float Rm0 = 0.0f, Rm1 = 0.0f;   // main channels: per-lane channel = c16
    float Rt0 = 0.0f, Rt1 = 0.0f;   // tail channels: per-lane channel = 16+(lane&3)

    float d0 = dpl[0];
    float d1 = dpl[Nn];

    #pragma unroll 2
    for (int t = 0; t < 16; ++t) {
        const float d0c = d0, d1c = d1;
        const int tn = (t + 1) & 15;        // clamped rotate: stays in-bounds
        d0 = dpl[16 * tn];
        d1 = dpl[Nn + 16 * tn];

        // row 0: a_jj = g0 * t^jj (c_jj folded into weights)
        short8 gA, gB;
        {
            const float u = d0c - mu0;
            const float g0 = EXP2F((-Kc * u) * u);
            const float tp = EXP2F(T04 * u);
            const float t2 = tp * tp, t3 = t2 * tp, t4 = t2 * t2;
            const float x1 = g0 * tp, x2 = g0 * t2, x3 = g0 * t3, x4 = g0 * t4;
            union { short8 s; unsigned u4[4]; } G;
            G.u4[0] = packbf(g0, x1);
            G.u4[1] = packbf(x2, x3);
            G.u4[2] = packbf(x4, x1 * t4);
            G.u4[3] = packbf(x2 * t4, x3 * t4);
            gA = G.s;
        }
        // row 1
        {
            const float u = d1c - mu0;
            const float g0 = EXP2F((-Kc * u) * u);
            const float tp = EXP2F(T04 * u);
            const float t2 = tp * tp, t3 = t2 * tp, t4 = t2 * t2;
            const float x1 = g0 * tp, x2 = g0 * t2, x3 = g0 * t3, x4 = g0 * t4;
            union { short8 s; unsigned u4[4]; } G;
            G.u4[0] = packbf(g0, x1);
            G.u4[1] = packbf(x2, x3);
            G.u4[2] = packbf(x4, x1 * t4);
            G.u4[3] = packbf(x2 * t4, x3 * t4);
            gB = G.s;
        }

        // 8 MFMAs (2 rows x 2 ntiles x hi/lo), bias as C operand
        floatx4 p00 = __builtin_amdgcn_mfma_f32_16x16x32_bf16(gA, whiK[0], bias0[0], 0, 0, 0);
        p00 = __builtin_amdgcn_mfma_f32_16x16x32_bf16(gA, wloK[0], p00, 0, 0, 0);
        floatx4 p01 = __builtin_amdgcn_mfma_f32_16x16x32_bf16(gA, whiK[1], bias0[1], 0, 0, 0);
        p01 = __builtin_amdgcn_mfma_f32_16x16x32_bf16(gA, wloK[1], p01, 0, 0, 0);
        floatx4 p10 = __builtin_amdgcn_mfma_f32_16x16x32_bf16(gB, whiK[0], bias1[0], 0, 0, 0);
        p10 = __builtin_amdgcn_mfma_f32_16x16x32_bf16(gB, wloK[0], p10, 0, 0, 0);
        floatx4 p11 = __builtin_amdgcn_mfma_f32_16x16x32_bf16(gB, whiK[1], bias1[1], 0, 0, 0);
        p11 = __builtin_amdgcn_mfma_f32_16x16x32_bf16(gB, wloK[1], p11, 0, 0, 0);

        // Tail compaction: valid tail data = regs 0..3 at lanes c16<4.
        // 3x update_dpp(row_shr:4m, bank_mask 1<<m) puts p[m] from lane c
        // onto lane c+4m+16q  ->  lane L holds element (jsub=4*(L>>4)+((L>>2)&3),
        // o = 16+(L&3)); bijective, so per-lane accumulation is channel-pure.
        int r0 = __float_as_int(p01[0]);
        r0 = __builtin_amdgcn_update_dpp(r0, __float_as_int(p01[1]), 0x114, 0xF, 0x2, false);
        r0 = __builtin_amdgcn_update_dpp(r0, __float_as_int(p01[2]), 0x118, 0xF, 0x4, false);
        r0 = __builtin_amdgcn_update_dpp(r0, __float_as_int(p01[3]), 0x11C, 0xF, 0x8, false);
        const float At0 = EXP2F(__int_as_float(r0)) + 1.0f;

        int r1 = __float_as_int(p11[0]);
        r1 = __builtin_amdgcn_update_dpp(r1, __float_as_int(p11[1]), 0x114, 0xF, 0x2, false);
        r1 = __builtin_amdgcn_update_dpp(r1, __float_as_int(p11[2]), 0x118, 0xF, 0x4, false);
        r1 = __builtin_amdgcn_update_dpp(r1, __float_as_int(p11[3]), 0x11C, 0xF, 0x8, false);
        const float At1 = EXP2F(__int_as_float(r1)) + 1.0f;

        // sigma sums: 4 main + 1 tail share ONE reciprocal per row
        {
            const float A0 = EXP2F(p00[0]) + 1.0f, A1 = EXP2F(p00[1]) + 1.0f;
            const float A2 = EXP2F(p00[2]) + 1.0f, A3 = EXP2F(p00[3]) + 1.0f;
            const float q01 = A0 * A1, q23 = A2 * A3;
            const float n4  = fmaf(q01, A2 + A3, q23 * (A0 + A1));
            const float d4  = q01 * q23;
            const float inv = RCPF(d4 * At0);
            Rm0 = fmaf(n4 * At0, inv, Rm0);   // += 1/A0+1/A1+1/A2+1/A3
            Rt0 = fmaf(d4, inv, Rt0);         // += 1/At0
        }
        {
            const float A0 = EXP2F(p10[0]) + 1.0f, A1 = EXP2F(p10[1]) + 1.0f;
            const float A2 = EXP2F(p10[2]) + 1.0f, A3 = EXP2F(p10[3]) + 1.0f;
            const float q01 = A0 * A1, q23 = A2 * A3;
            const float n4  = fmaf(q01, A2 + A3, q23 * (A0 + A1));
            const float d4  = q01 * q23;
            const float inv = RCPF(d4 * At1);
            Rm1 = fmaf(n4 * At1, inv, Rm1);
            Rt1 = fmaf(d4, inv, Rt1);
        }
    }

    // main channels: reduce over quads (channel = c16 fixed per lane)
    Rm0 += __shfl_xor(Rm0, 16, 64);  Rm0 += __shfl_xor(Rm0, 32, 64);
    Rm1 += __shfl_xor(Rm1, 16, 64);  Rm1 += __shfl_xor(Rm1, 32, 64);
    // tail channels: reduce over all lanes sharing (lane&3)
    Rt0 += __shfl_xor(Rt0, 4, 64);   Rt0 += __shfl_xor(Rt0, 8, 64);
    Rt0 += __shfl_xor(Rt0, 16, 64);  Rt0 += __shfl_xor(Rt0, 32, 64);
    Rt1 += __shfl_xor(Rt1, 4, 64);   Rt1 += __shfl_xor(Rt1, 8, 64);
    Rt1 += __shfl_xor(Rt1, 16, 64);  Rt1 += __shfl_xor(Rt1, 32, 64);

    // folded top-MLP coefficients (channels 0..15 at c16; 16..19 at lane&3)
    const int om = c16;              // always < Ee
    const int ot = 16 + (lane & 3);  // always < Ee
    float uom = 0.0f, uot = 0.0f;
    #pragma unroll
    for (int p = 0; p < 10; ++p) {
        uom = fmaf(W2[p], W1[p * Ee + om], uom);
        uot = fmaf(W2[p], W1[p * Ee + ot], uot);
    }
    const float cfm0 = m0 * emb[zu0 * Ee + om];
    const float cfm1 = m1 * emb[zu1 * Ee + om];
    const float cft0 = m0 * emb[zu0 * Ee + ot];
    const float cft1 = m1 * emb[zu1 * Ee + ot];

    // epilogue: th = tanh(cf + m*(256 - 2R)); e = sum_o u[o]*th[o].
    // Tail terms appear 4x per 16-lane reduction group -> scale 0.25.
    float e = 0.0f;
    e = fmaf(tanhfast(cfm0 + m0 * (256.0f - 2.0f * Rm0)), uom, e);
    e = fmaf(tanhfast(cfm1 + m1 * (256.0f - 2.0f * Rm1)), uom, e);
    e = fmaf(tanhfast(cft0 + m0 * (256.0f - 2.0f * Rt0)), 0.25f * uot, e);
    e = fmaf(tanhfast(cft1 + m1 * (256.0f - 2.0f * Rt1)), 0.25f * uot, e);
    e += __shfl_xor(e, 1, 64);
    e += __shfl_xor(e, 2, 64);
    e += __shfl_xor(e, 4, 64);
    e += __shfl_xor(e, 8, 64);

    // block reduce: 4 waves -> one plain store (NO atomics)
    __shared__ float sE[4];
    if (lane == 0) sE[wave] = e;
    __syncthreads();
    if (tid == 0)
        part[blk] = sE[0] + sE[1] + sE[2] + sE[3];
}

// 64 blocks x 64 lanes: out[b] = sum of 32 block-partials + 256*C0
__global__ __launch_bounds__(64) void dtnn_reduce(
    const float* __restrict__ part,
    const float* __restrict__ b1, const float* __restrict__ W2,
    const float* __restrict__ b2, float* __restrict__ out)
{
    const int b = blockIdx.x;
    const int t = threadIdx.x;
    float v = (t < 32) ? part[b * 32 + t] : 0.0f;
    v += __shfl_xor(v, 1, 64);
    v += __shfl_xor(v, 2, 64);
    v += __shfl_xor(v, 4, 64);
    v += __shfl_xor(v, 8, 64);
    v += __shfl_xor(v, 16, 64);
    if (t == 0) {
        float c0 = b2[0];
        #pragma unroll
        for (int p = 0; p < 10; ++p) c0 = fmaf(W2[p], b1[p], c0);
        out[b] = v + __shfl(v, 32, 64) * 0.0f + 256.0f * c0 + __shfl_xor(v, 32, 64);
    }
}

extern "C" void kernel_launch(void* const* d_in, const int* in_sizes, int n_in,
                              void* d_out, int out_size, void* d_ws, size_t ws_size,
                              hipStream_t stream) {
    const int*   z    = (const int*)  d_in[0];
    const float* dist = (const float*)d_in[1];
    const float* emb  = (const float*)d_in[2];
    const float* Vw   = (const float*)d_in[3];
    const float* Vb   = (const float*)d_in[4];
    const float* W1   = (const float*)d_in[5];
    const float* b1   = (const float*)d_in[6];
    const float* W2   = (const float*)d_in[7];
    const float* b2   = (const float*)d_in[8];
    float* out = (float*)d_out;

    float* partP = (float*)d_ws;   // [NBLK]

    // 2 dispatches: fat main (2 rows/wave, self-contained) + tiny reduce
    dtnn_main<<<NBLK, 256, 0, stream>>>(z, dist, emb, Vw, Vb, W1, W2, partP);
    dtnn_reduce<<<Bsz, 64, 0, stream>>>(partP, b1, W2, b2, out);
}

// Round 2
// 114.179 us; speedup vs baseline: 1.0678x; 1.0525x over previous
//
#include <hip/hip_runtime.h>

#define Bsz 64
#define Nn  256
#define Ee  20   // atom embedding dim
#define Dd  25   // gaussian centers
#define NBLK 2048  // 2048 blocks x 4 waves x 2 rows = 16384 (b,i) rows

using short8  = __attribute__((ext_vector_type(8))) short;  // 8 bf16 (4 VGPRs)
using floatx4 = __attribute__((ext_vector_type(4))) float;  // 4 fp32 acc

#if __has_builtin(__builtin_amdgcn_exp2f)
#define EXP2F(x) __builtin_amdgcn_exp2f(x)
#else
#define EXP2F(x) __expf(0.6931471805599453f * (x))
#endif
#if __has_builtin(__builtin_amdgcn_rcpf)
#define RCPF(x) __builtin_amdgcn_rcpf(x)
#else
#define RCPF(x) (1.0f / (x))
#endif

__device__ __forceinline__ short f2bf(float x) {            // RNE fp32->bf16
    unsigned u = __float_as_uint(x);
    unsigned r = (u + 0x7FFFu + ((u >> 16) & 1u)) >> 16;
    return (short)r;
}
__device__ __forceinline__ float bf2f(short h) {
    return __uint_as_float(((unsigned)(unsigned short)h) << 16);
}
__device__ __forceinline__ float tanhfast(float x) {
    float e = __expf(2.0f * x);
    return 1.0f - 2.0f / (e + 1.0f);
}
// pack two fp32 -> two bf16 in one VALU op (RNE). dst.lo=cvt(a), dst.hi=cvt(b)
__device__ __forceinline__ unsigned packbf(float a, float b) {
    unsigned r;
    asm("v_cvt_pk_bf16_f32 %0, %1, %2" : "=v"(r) : "v"(a), "v"(b));
    return r;
}

// Main kernel. Each wave owns 2 rows (b,i0),(b,i0+1); 4 waves/block share b.
// d-distribution: 8 coalesced global loads -> wave-private LDS -> per-iter
// ds_read_b32 broadcast (16 banks x 4-lane broadcast, conflict-free, imm offs).
// Tail channels (o=16..19): DPP-compacted so each lane exponentiates exactly
// one VALID tail element per (row,iter); per-lane tail channel = 16+(lane&3).
__global__ __launch_bounds__(256, 4) void dtnn_main(
    const int*   __restrict__ z,     // [B,N]
    const float* __restrict__ dist,  // [B,N,N]
    const float* __restrict__ emb,   // [N,E]
    const float* __restrict__ Vw,    // [E,45]
    const float* __restrict__ Vb,    // [E]
    const float* __restrict__ W1,    // [10,E]
    const float* __restrict__ W2,    // [1,10]
    float*       __restrict__ part)  // [NBLK]
{
    const int tid  = threadIdx.x;
    const int lane = tid & 63;
    const int wave = tid >> 6;
    const int blk  = blockIdx.x;
    const int b    = blk >> 5;                       // 32 blocks per batch
    const int i0   = ((blk & 31) << 3) | (wave << 1);// rows i0, i0+1

    const int c16  = lane & 15;
    const int quad = lane >> 4;
    const int k0   = quad * 8;
    const float Kc = 2.8853900817779268f;            // 2*log2(e)
    const float T04 = 1.1541560327111707f;           // 0.4*Kc

    // wave-private LDS staging of the 2 dist rows (no barrier needed)
    __shared__ float sD[4][2][256];
    float* sDw = &sD[wave][0][0];

    // 8 coalesced row loads issued FIRST; latency hides under weight prologue
    const float* dr0 = dist + ((size_t)b * Nn + i0) * Nn;
    const float a0r = dr0[lane],        a1r = dr0[lane + 64];
    const float a2r = dr0[lane + 128],  a3r = dr0[lane + 192];
    const float b0r = dr0[Nn + lane],       b1r = dr0[Nn + lane + 64];
    const float b2r = dr0[Nn + lane + 128], b3r = dr0[Nn + lane + 192];

    const int zi0 = z[b * Nn + i0];
    const int zi1 = z[b * Nn + i0 + 1];
    const int zu0 = __builtin_amdgcn_readfirstlane(zi0);  // wave-uniform
    const int zu1 = __builtin_amdgcn_readfirstlane(zi1);
    const float m0 = (zu0 != 0) ? 1.0f : 0.0f;
    const float m1 = (zu1 != 0) ? 1.0f : 0.0f;

    // Gaussian step constants c_jj = e^{-0.08 jj^2}, folded into the weights.
    const float cj[8] = {1.0f, 0.9231163463866358f, 0.7261490370736909f,
                         0.48675225595997157f, 0.2780373004531941f,
                         0.1353352832366127f, 0.05613476283303940f,
                         0.019841459768337877f};

    // weight fragments (divergent gathers; L1-hot) + per-row bias
    short8 whiK[2], wloK[2];
    floatx4 bias0[2], bias1[2];
    #pragma unroll
    for (int nt = 0; nt < 2; ++nt) {
        const int o = nt * 16 + c16;
        const bool valid = (o < Ee);
        const int oc = valid ? o : 0;                 // clamp vs OOB speculation
        #pragma unroll
        for (int jj = 0; jj < 8; ++jj) {
            const int k = k0 + jj;
            const float v = (valid && k < Dd)
                          ? Kc * cj[jj] * Vw[oc * 45 + 20 + k] : 0.0f;
            const short h = f2bf(v);
            whiK[nt][jj] = h;
            wloK[nt][jj] = f2bf(v - bf2f(h));
        }
        // A[o] = Kc*(Vb[o] + m * Vw[o,:20].emb[z])
        float dot0 = 0.0f, dot1 = 0.0f;
        #pragma unroll
        for (int f = 0; f < Ee; ++f) {
            const float w = valid ? Vw[oc * 45 + f] : 0.0f;
            dot0 = fmaf(w, emb[zu0 * Ee + f], dot0);   // emb: s_loads (uniform)
            dot1 = fmaf(w, emb[zu1 * Ee + f], dot1);
        }
        const float vb = valid ? Vb[oc] : 0.0f;
        const float A0 = Kc * (vb + m0 * dot0);
        const float A1 = Kc * (vb + m1 * dot1);
        bias0[nt] = (floatx4){A0, A0, A0, A0};
        bias1[nt] = (floatx4){A1, A1, A1, A1};
    }

    // stage rows into wave-private LDS (2-way bank alias on writes = free;
    // compiler inserts lgkmcnt before first dependent ds_read)
    sDw[lane]       = a0r;  sDw[lane + 64]  = a1r;
    sDw[lane + 128] = a2r;  sDw[lane + 192] = a3r;
    sDw[256 + lane]       = b0r;  sDw[256 + lane + 64]  = b1r;
    sDw[256 + lane + 128] = b2r;  sDw[256 + lane + 192] = b3r;

    // ---- main loop: 16 j-tiles x 2 rows; sum tanh = 256 - 2*sum sigma
    // FULL unroll: ds_read addresses fold to base + imm offset (0 addr VALU),
    // and the scheduler gets a 16-iter window to overlap phases.
    const float mu0 = 0.2f * (float)k0;
    float Rm0 = 0.0f, Rm1 = 0.0f;   // main channels: per-lane channel = c16
    float Rt0 = 0.0f, Rt1 = 0.0f;   // tail channels: per-lane channel = 16+(lane&3)

    #pragma unroll
    for (int t = 0; t < 16; ++t) {
        const float d0c = sDw[16 * t + c16];          // 4-lane broadcast reads
        const float d1c = sDw[256 + 16 * t + c16];

        // row 0: a_jj = g0 * t^jj (c_jj folded into weights)
        short8 gA, gB;
        {
            const float u = d0c - mu0;
            const float g0 = EXP2F((-Kc * u) * u);
            const float tp = EXP2F(T04 * u);
            const float t2 = tp * tp, t3 = t2 * tp, t4 = t2 * t2;
            const float x1 = g0 * tp, x2 = g0 * t2, x3 = g0 * t3, x4 = g0 * t4;
            union { short8 s; unsigned u4[4]; } G;
            G.u4[0] = packbf(g0, x1);
            G.u4[1] = packbf(x2, x3);
            G.u4[2] = packbf(x4, x1 * t4);
            G.u4[3] = packbf(x2 * t4, x3 * t4);
            gA = G.s;
        }
        // row 1
        {
            const float u = d1c - mu0;
            const float g0 = EXP2F((-Kc * u) * u);
            const float tp = EXP2F(T04 * u);
            const float t2 = tp * tp, t3 = t2 * tp, t4 = t2 * t2;
            const float x1 = g0 * tp, x2 = g0 * t2, x3 = g0 * t3, x4 = g0 * t4;
            union { short8 s; unsigned u4[4]; } G;
            G.u4[0] = packbf(g0, x1);
            G.u4[1] = packbf(x2, x3);
            G.u4[2] = packbf(x4, x1 * t4);
            G.u4[3] = packbf(x2 * t4, x3 * t4);
            gB = G.s;
        }

        // 8 MFMAs (2 rows x 2 ntiles x hi/lo), bias as C operand
        floatx4 p00 = __builtin_amdgcn_mfma_f32_16x16x32_bf16(gA, whiK[0], bias0[0], 0, 0, 0);
        p00 = __builtin_amdgcn_mfma_f32_16x16x32_bf16(gA, wloK[0], p00, 0, 0, 0);
        floatx4 p01 = __builtin_amdgcn_mfma_f32_16x16x32_bf16(gA, whiK[1], bias0[1], 0, 0, 0);
        p01 = __builtin_amdgcn_mfma_f32_16x16x32_bf16(gA, wloK[1], p01, 0, 0, 0);
        floatx4 p10 = __builtin_amdgcn_mfma_f32_16x16x32_bf16(gB, whiK[0], bias1[0], 0, 0, 0);
        p10 = __builtin_amdgcn_mfma_f32_16x16x32_bf16(gB, wloK[0], p10, 0, 0, 0);
        floatx4 p11 = __builtin_amdgcn_mfma_f32_16x16x32_bf16(gB, whiK[1], bias1[1], 0, 0, 0);
        p11 = __builtin_amdgcn_mfma_f32_16x16x32_bf16(gB, wloK[1], p11, 0, 0, 0);

        // Tail compaction: valid tail data = regs 0..3 at lanes c16<4.
        // 3x update_dpp(row_shr:4m, bank_mask 1<<m) -> lane L holds element
        // (jsub=4*(L>>4)+((L>>2)&3), o=16+(L&3)); bijective.
        int r0 = __float_as_int(p01[0]);
        r0 = __builtin_amdgcn_update_dpp(r0, __float_as_int(p01[1]), 0x114, 0xF, 0x2, false);
        r0 = __builtin_amdgcn_update_dpp(r0, __float_as_int(p01[2]), 0x118, 0xF, 0x4, false);
        r0 = __builtin_amdgcn_update_dpp(r0, __float_as_int(p01[3]), 0x11C, 0xF, 0x8, false);
        const float At0 = EXP2F(__int_as_float(r0)) + 1.0f;

        int r1 = __float_as_int(p11[0]);
        r1 = __builtin_amdgcn_update_dpp(r1, __float_as_int(p11[1]), 0x114, 0xF, 0x2, false);
        r1 = __builtin_amdgcn_update_dpp(r1, __float_as_int(p11[2]), 0x118, 0xF, 0x4, false);
        r1 = __builtin_amdgcn_update_dpp(r1, __float_as_int(p11[3]), 0x11C, 0xF, 0x8, false);
        const float At1 = EXP2F(__int_as_float(r1)) + 1.0f;

        // sigma sums: 4 main + 1 tail share ONE reciprocal per row
        {
            const float A0 = EXP2F(p00[0]) + 1.0f, A1 = EXP2F(p00[1]) + 1.0f;
            const float A2 = EXP2F(p00[2]) + 1.0f, A3 = EXP2F(p00[3]) + 1.0f;
            const float q01 = A0 * A1, q23 = A2 * A3;
            const float n4  = fmaf(q01, A2 + A3, q23 * (A0 + A1));
            const float d4  = q01 * q23;
            const float inv = RCPF(d4 * At0);
            Rm0 = fmaf(n4 * At0, inv, Rm0);   // += 1/A0+1/A1+1/A2+1/A3
            Rt0 = fmaf(d4, inv, Rt0);         // += 1/At0
        }
        {
            const float A0 = EXP2F(p10[0]) + 1.0f, A1 = EXP2F(p10[1]) + 1.0f;
            const float A2 = EXP2F(p10[2]) + 1.0f, A3 = EXP2F(p10[3]) + 1.0f;
            const float q01 = A0 * A1, q23 = A2 * A3;
            const float n4  = fmaf(q01, A2 + A3, q23 * (A0 + A1));
            const float d4  = q01 * q23;
            const float inv = RCPF(d4 * At1);
            Rm1 = fmaf(n4 * At1, inv, Rm1);
            Rt1 = fmaf(d4, inv, Rt1);
        }
    }

    // main channels: reduce over quads (channel = c16 fixed per lane)
    Rm0 += __shfl_xor(Rm0, 16, 64);  Rm0 += __shfl_xor(Rm0, 32, 64);
    Rm1 += __shfl_xor(Rm1, 16, 64);  Rm1 += __shfl_xor(Rm1, 32, 64);
    // tail channels: reduce over all lanes sharing (lane&3)
    Rt0 += __shfl_xor(Rt0, 4, 64);   Rt0 += __shfl_xor(Rt0, 8, 64);
    Rt0 += __shfl_xor(Rt0, 16, 64);  Rt0 += __shfl_xor(Rt0, 32, 64);
    Rt1 += __shfl_xor(Rt1, 4, 64);   Rt1 += __shfl_xor(Rt1, 8, 64);
    Rt1 += __shfl_xor(Rt1, 16, 64);  Rt1 += __shfl_xor(Rt1, 32, 64);

    // folded top-MLP coefficients (channels 0..15 at c16; 16..19 at lane&3)
    const int om = c16;              // always < Ee
    const int ot = 16 + (lane & 3);  // always < Ee
    float uom = 0.0f, uot = 0.0f;
    #pragma unroll
    for (int p = 0; p < 10; ++p) {
        uom = fmaf(W2[p], W1[p * Ee + om], uom);
        uot = fmaf(W2[p], W1[p * Ee + ot], uot);
    }
    const float cfm0 = m0 * emb[zu0 * Ee + om];
    const float cfm1 = m1 * emb[zu1 * Ee + om];
    const float cft0 = m0 * emb[zu0 * Ee + ot];
    const float cft1 = m1 * emb[zu1 * Ee + ot];

    // epilogue: th = tanh(cf + m*(256 - 2R)); e = sum_o u[o]*th[o].
    // Tail terms appear 4x per 16-lane reduction group -> scale 0.25.
    float e = 0.0f;
    e = fmaf(tanhfast(cfm0 + m0 * (256.0f - 2.0f * Rm0)), uom, e);
    e = fmaf(tanhfast(cfm1 + m1 * (256.0f - 2.0f * Rm1)), uom, e);
    e = fmaf(tanhfast(cft0 + m0 * (256.0f - 2.0f * Rt0)), 0.25f * uot, e);
    e = fmaf(tanhfast(cft1 + m1 * (256.0f - 2.0f * Rt1)), 0.25f * uot, e);
    e += __shfl_xor(e, 1, 64);
    e += __shfl_xor(e, 2, 64);
    e += __shfl_xor(e, 4, 64);
    e += __shfl_xor(e, 8, 64);

    // block reduce: 4 waves -> one plain store (NO atomics)
    __shared__ float sE[4];
    if (lane == 0) sE[wave] = e;
    __syncthreads();
    if (tid == 0)
        part[blk] = sE[0] + sE[1] + sE[2] + sE[3];
}

// 64 blocks x 64 lanes: out[b] = sum of 32 block-partials + 256*C0
__global__ __launch_bounds__(64) void dtnn_reduce(
    const float* __restrict__ part,
    const float* __restrict__ b1, const float* __restrict__ W2,
    const float* __restrict__ b2, float* __restrict__ out)
{
    const int b = blockIdx.x;
    const int t = threadIdx.x;
    float v = (t < 32) ? part[b * 32 + t] : 0.0f;
    v += __shfl_xor(v, 1, 64);
    v += __shfl_xor(v, 2, 64);
    v += __shfl_xor(v, 4, 64);
    v += __shfl_xor(v, 8, 64);
    v += __shfl_xor(v, 16, 64);
    if (t == 0) {
        float c0 = b2[0];
        #pragma unroll
        for (int p = 0; p < 10; ++p) c0 = fmaf(W2[p], b1[p], c0);
        out[b] = v + __shfl(v, 32, 64) * 0.0f + 256.0f * c0 + __shfl_xor(v, 32, 64);
    }
}

extern "C" void kernel_launch(void* const* d_in, const int* in_sizes, int n_in,
                              void* d_out, int out_size, void* d_ws, size_t ws_size,
                              hipStream_t stream) {
    const int*   z    = (const int*)  d_in[0];
    const float* dist = (const float*)d_in[1];
    const float* emb  = (const float*)d_in[2];
    const float* Vw   = (const float*)d_in[3];
    const float* Vb   = (const float*)d_in[4];
    const float* W1   = (const float*)d_in[5];
    const float* b1   = (const float*)d_in[6];
    const float* W2   = (const float*)d_in[7];
    const float* b2   = (const float*)d_in[8];
    float* out = (float*)d_out;

    float* partP = (float*)d_ws;   // [NBLK]

    // 2 dispatches: fat main (2 rows/wave, self-contained) + tiny reduce
    dtnn_main<<<NBLK, 256, 0, stream>>>(z, dist, emb, Vw, Vb, W1, W2, partP);
    dtnn_reduce<<<Bsz, 64, 0, stream>>>(partP, b1, W2, b2, out);
}

// Round 3
// 113.502 us; speedup vs baseline: 1.0742x; 1.0060x over previous
//
#include <hip/hip_runtime.h>

#define Bsz 64
#define Nn  256
#define Ee  20   // atom embedding dim
#define Dd  25   // gaussian centers
#define NBLK 2048  // 2048 blocks x 4 waves x 2 rows = 16384 (b,i) rows

using short8  = __attribute__((ext_vector_type(8))) short;  // 8 bf16 (4 VGPRs)
using floatx4 = __attribute__((ext_vector_type(4))) float;  // 4 fp32 acc

#if __has_builtin(__builtin_amdgcn_exp2f)
#define EXP2F(x) __builtin_amdgcn_exp2f(x)
#else
#define EXP2F(x) __expf(0.6931471805599453f * (x))
#endif
#if __has_builtin(__builtin_amdgcn_rcpf)
#define RCPF(x) __builtin_amdgcn_rcpf(x)
#else
#define RCPF(x) (1.0f / (x))
#endif

__device__ __forceinline__ short f2bf(float x) {            // RNE fp32->bf16
    unsigned u = __float_as_uint(x);
    unsigned r = (u + 0x7FFFu + ((u >> 16) & 1u)) >> 16;
    return (short)r;
}
__device__ __forceinline__ float bf2f(short h) {
    return __uint_as_float(((unsigned)(unsigned short)h) << 16);
}
__device__ __forceinline__ float tanhfast(float x) {
    float e = __expf(2.0f * x);
    return 1.0f - 2.0f / (e + 1.0f);
}
// pack two fp32 -> two bf16 in one VALU op (RNE). dst.lo=cvt(a), dst.hi=cvt(b)
__device__ __forceinline__ unsigned packbf(float a, float b) {
    unsigned r;
    asm("v_cvt_pk_bf16_f32 %0, %1, %2" : "=v"(r) : "v"(a), "v"(b));
    return r;
}

// serial power ladder: features g0 * tp^j, j=0..7 (c_j folded into weights)
__device__ __forceinline__ short8 ladder8(float g0, float tp) {
    const float x1 = g0 * tp;
    const float x2 = x1 * tp;
    const float x3 = x2 * tp;
    const float x4 = x3 * tp;
    const float x5 = x4 * tp;
    const float x6 = x5 * tp;
    const float x7 = x6 * tp;
    union { short8 s; unsigned u4[4]; } G;
    G.u4[0] = packbf(g0, x1);
    G.u4[1] = packbf(x2, x3);
    G.u4[2] = packbf(x4, x5);
    G.u4[3] = packbf(x6, x7);
    return G.s;
}

// sigma partials: n4/d4 rational form of 1/A0+1/A1+1/A2+1/A3, A=2^p+1
__device__ __forceinline__ void sigParts(floatx4 p, float& n4, float& d4) {
    const float A0 = EXP2F(p[0]) + 1.0f, A1 = EXP2F(p[1]) + 1.0f;
    const float A2 = EXP2F(p[2]) + 1.0f, A3 = EXP2F(p[3]) + 1.0f;
    const float q01 = A0 * A1, q23 = A2 * A3;
    n4 = fmaf(q01, A2 + A3, q23 * (A0 + A1));
    d4 = q01 * q23;
}

// Tail compaction: valid tail data = regs 0..3 at lanes c16<4.
// 3x update_dpp(row_shr:4m, bank_mask 1<<m) -> lane L holds element
// (jsub=4*(L>>4)+((L>>2)&3), o=16+(L&3)); bijective. Returns A=2^x+1.
__device__ __forceinline__ float tailA(floatx4 p) {
    int r = __float_as_int(p[0]);
    r = __builtin_amdgcn_update_dpp(r, __float_as_int(p[1]), 0x114, 0xF, 0x2, false);
    r = __builtin_amdgcn_update_dpp(r, __float_as_int(p[2]), 0x118, 0xF, 0x4, false);
    r = __builtin_amdgcn_update_dpp(r, __float_as_int(p[3]), 0x11C, 0xF, 0x8, false);
    return EXP2F(__int_as_float(r)) + 1.0f;
}

// Main kernel. Each wave owns 2 rows (b,i0),(b,i0+1); 4 waves/block share b.
// d via wave-private LDS broadcast. Loop processes 2 j-tiles jointly with
// explicit phase interleave to force cross-iteration ILP (latency hiding).
__global__ __launch_bounds__(256, 4) void dtnn_main(
    const int*   __restrict__ z,     // [B,N]
    const float* __restrict__ dist,  // [B,N,N]
    const float* __restrict__ emb,   // [N,E]
    const float* __restrict__ Vw,    // [E,45]
    const float* __restrict__ Vb,    // [E]
    const float* __restrict__ W1,    // [10,E]
    const float* __restrict__ W2,    // [1,10]
    float*       __restrict__ part)  // [NBLK]
{
    const int tid  = threadIdx.x;
    const int lane = tid & 63;
    const int wave = tid >> 6;
    const int blk  = blockIdx.x;
    const int b    = blk >> 5;                       // 32 blocks per batch
    const int i0   = ((blk & 31) << 3) | (wave << 1);// rows i0, i0+1

    const int c16  = lane & 15;
    const int quad = lane >> 4;
    const int k0   = quad * 8;
    const float Kc = 2.8853900817779268f;            // 2*log2(e)
    const float T04 = 1.1541560327111707f;           // 0.4*Kc

    // wave-private LDS staging of the 2 dist rows (no barrier needed)
    __shared__ float sD[4][2][256];
    float* sDw = &sD[wave][0][0];

    // 8 coalesced row loads issued FIRST; latency hides under weight prologue
    const float* dr0 = dist + ((size_t)b * Nn + i0) * Nn;
    const float a0r = dr0[lane],        a1r = dr0[lane + 64];
    const float a2r = dr0[lane + 128],  a3r = dr0[lane + 192];
    const float b0r = dr0[Nn + lane],       b1r = dr0[Nn + lane + 64];
    const float b2r = dr0[Nn + lane + 128], b3r = dr0[Nn + lane + 192];

    const int zi0 = z[b * Nn + i0];
    const int zi1 = z[b * Nn + i0 + 1];
    const int zu0 = __builtin_amdgcn_readfirstlane(zi0);  // wave-uniform
    const int zu1 = __builtin_amdgcn_readfirstlane(zi1);
    const float m0 = (zu0 != 0) ? 1.0f : 0.0f;
    const float m1 = (zu1 != 0) ? 1.0f : 0.0f;

    // Gaussian step constants c_jj = e^{-0.08 jj^2}, folded into the weights.
    const float cj[8] = {1.0f, 0.9231163463866358f, 0.7261490370736909f,
                         0.48675225595997157f, 0.2780373004531941f,
                         0.1353352832366127f, 0.05613476283303940f,
                         0.019841459768337877f};

    // weight fragments (divergent gathers; L1-hot) + per-row bias
    short8 whiK[2], wloK[2];
    floatx4 bias0[2], bias1[2];
    #pragma unroll
    for (int nt = 0; nt < 2; ++nt) {
        const int o = nt * 16 + c16;
        const bool valid = (o < Ee);
        const int oc = valid ? o : 0;                 // clamp vs OOB speculation
        #pragma unroll
        for (int jj = 0; jj < 8; ++jj) {
            const int k = k0 + jj;
            const float v = (valid && k < Dd)
                          ? Kc * cj[jj] * Vw[oc * 45 + 20 + k] : 0.0f;
            const short h = f2bf(v);
            whiK[nt][jj] = h;
            wloK[nt][jj] = f2bf(v - bf2f(h));
        }
        // A[o] = Kc*(Vb[o] + m * Vw[o,:20].emb[z])
        float dot0 = 0.0f, dot1 = 0.0f;
        #pragma unroll
        for (int f = 0; f < Ee; ++f) {
            const float w = valid ? Vw[oc * 45 + f] : 0.0f;
            dot0 = fmaf(w, emb[zu0 * Ee + f], dot0);   // emb: s_loads (uniform)
            dot1 = fmaf(w, emb[zu1 * Ee + f], dot1);
        }
        const float vb = valid ? Vb[oc] : 0.0f;
        const float A0 = Kc * (vb + m0 * dot0);
        const float A1 = Kc * (vb + m1 * dot1);
        bias0[nt] = (floatx4){A0, A0, A0, A0};
        bias1[nt] = (floatx4){A1, A1, A1, A1};
    }

    // stage rows into wave-private LDS
    sDw[lane]       = a0r;  sDw[lane + 64]  = a1r;
    sDw[lane + 128] = a2r;  sDw[lane + 192] = a3r;
    sDw[256 + lane]       = b0r;  sDw[256 + lane + 64]  = b1r;
    sDw[256 + lane + 128] = b2r;  sDw[256 + lane + 192] = b3r;

    // ---- main loop: 8 blocks x 2 j-tiles x 2 rows, phase-interleaved
    const float mu0 = 0.2f * (float)k0;
    float Rm0 = 0.0f, Rm1 = 0.0f;   // main channels: per-lane channel = c16
    float Rt0 = 0.0f, Rt1 = 0.0f;   // tail channels: per-lane channel = 16+(lane&3)

    #pragma unroll
    for (int tt = 0; tt < 8; ++tt) {
        const int t0 = 2 * tt, t1 = 2 * tt + 1;
        // 4 broadcast d-reads (imm offsets off sDw+c16 base)
        const float dA0 = sDw[16 * t0 + c16];         // row0, iter0
        const float dB0 = sDw[256 + 16 * t0 + c16];   // row1, iter0
        const float dA1 = sDw[16 * t1 + c16];         // row0, iter1
        const float dB1 = sDw[256 + 16 * t1 + c16];   // row1, iter1

        // phase 1: all 8 gaussian exps issued together (fills trans pipe)
        const float uA0 = dA0 - mu0, uB0 = dB0 - mu0;
        const float uA1 = dA1 - mu0, uB1 = dB1 - mu0;
        const float gA0 = EXP2F((-Kc * uA0) * uA0);
        const float gB0 = EXP2F((-Kc * uB0) * uB0);
        const float gA1 = EXP2F((-Kc * uA1) * uA1);
        const float gB1 = EXP2F((-Kc * uB1) * uB1);
        const float tA0 = EXP2F(T04 * uA0);
        const float tB0 = EXP2F(T04 * uB0);
        const float tA1 = EXP2F(T04 * uA1);
        const float tB1 = EXP2F(T04 * uB1);

        // phase 2: 4 independent serial ladders -> bf16 fragments
        const short8 GA0 = ladder8(gA0, tA0);
        const short8 GB0 = ladder8(gB0, tB0);
        const short8 GA1 = ladder8(gA1, tA1);
        const short8 GB1 = ladder8(gB1, tB1);

        // phase 3: iter0 MFMAs (bias as C), then iter0 transcendentals
        floatx4 p00 = __builtin_amdgcn_mfma_f32_16x16x32_bf16(GA0, whiK[0], bias0[0], 0, 0, 0);
        p00 = __builtin_amdgcn_mfma_f32_16x16x32_bf16(GA0, wloK[0], p00, 0, 0, 0);
        floatx4 p01 = __builtin_amdgcn_mfma_f32_16x16x32_bf16(GA0, whiK[1], bias0[1], 0, 0, 0);
        p01 = __builtin_amdgcn_mfma_f32_16x16x32_bf16(GA0, wloK[1], p01, 0, 0, 0);
        floatx4 p10 = __builtin_amdgcn_mfma_f32_16x16x32_bf16(GB0, whiK[0], bias1[0], 0, 0, 0);
        p10 = __builtin_amdgcn_mfma_f32_16x16x32_bf16(GB0, wloK[0], p10, 0, 0, 0);
        floatx4 p11 = __builtin_amdgcn_mfma_f32_16x16x32_bf16(GB0, whiK[1], bias1[1], 0, 0, 0);
        p11 = __builtin_amdgcn_mfma_f32_16x16x32_bf16(GB0, wloK[1], p11, 0, 0, 0);

        const float At0a = tailA(p01);
        const float At1a = tailA(p11);
        float n0a, d0a, n1a, d1a;
        sigParts(p00, n0a, d0a);
        sigParts(p10, n1a, d1a);

        // phase 4: iter1 MFMAs, then iter1 transcendentals
        floatx4 q00 = __builtin_amdgcn_mfma_f32_16x16x32_bf16(GA1, whiK[0], bias0[0], 0, 0, 0);
        q00 = __builtin_amdgcn_mfma_f32_16x16x32_bf16(GA1, wloK[0], q00, 0, 0, 0);
        floatx4 q01 = __builtin_amdgcn_mfma_f32_16x16x32_bf16(GA1, whiK[1], bias0[1], 0, 0, 0);
        q01 = __builtin_amdgcn_mfma_f32_16x16x32_bf16(GA1, wloK[1], q01, 0, 0, 0);
        floatx4 q10 = __builtin_amdgcn_mfma_f32_16x16x32_bf16(GB1, whiK[0], bias1[0], 0, 0, 0);
        q10 = __builtin_amdgcn_mfma_f32_16x16x32_bf16(GB1, wloK[0], q10, 0, 0, 0);
        floatx4 q11 = __builtin_amdgcn_mfma_f32_16x16x32_bf16(GB1, whiK[1], bias1[1], 0, 0, 0);
        q11 = __builtin_amdgcn_mfma_f32_16x16x32_bf16(GB1, wloK[1], q11, 0, 0, 0);

        const float At0b = tailA(q01);
        const float At1b = tailA(q11);
        float n0b, d0b, n1b, d1b;
        sigParts(q00, n0b, d0b);
        sigParts(q10, n1b, d1b);

        // phase 5: one reciprocal per row per 2 iters (magnitude-safe:
        // |preact*Kc| <~ 12 -> product <= 2^120 < FLT_MAX; realistic ~1e6)
        {
            const float Da = d0a * At0a, Db = d0b * At0b;
            const float inv = RCPF(Da * Db);
            const float ea = Db * inv, eb = Da * inv;  // 1/Da, 1/Db
            Rm0 = fmaf(n0a * At0a, ea, Rm0);
            Rm0 = fmaf(n0b * At0b, eb, Rm0);
            Rt0 = fmaf(d0a, ea, Rt0);                  // 1/At0a
            Rt0 = fmaf(d0b, eb, Rt0);                  // 1/At0b
        }
        {
            const float Da = d1a * At1a, Db = d1b * At1b;
            const float inv = RCPF(Da * Db);
            const float ea = Db * inv, eb = Da * inv;
            Rm1 = fmaf(n1a * At1a, ea, Rm1);
            Rm1 = fmaf(n1b * At1b, eb, Rm1);
            Rt1 = fmaf(d1a, ea, Rt1);
            Rt1 = fmaf(d1b, eb, Rt1);
        }
    }

    // main channels: reduce over quads (channel = c16 fixed per lane)
    Rm0 += __shfl_xor(Rm0, 16, 64);  Rm0 += __shfl_xor(Rm0, 32, 64);
    Rm1 += __shfl_xor(Rm1, 16, 64);  Rm1 += __shfl_xor(Rm1, 32, 64);
    // tail channels: reduce over all lanes sharing (lane&3)
    Rt0 += __shfl_xor(Rt0, 4, 64);   Rt0 += __shfl_xor(Rt0, 8, 64);
    Rt0 += __shfl_xor(Rt0, 16, 64);  Rt0 += __shfl_xor(Rt0, 32, 64);
    Rt1 += __shfl_xor(Rt1, 4, 64);   Rt1 += __shfl_xor(Rt1, 8, 64);
    Rt1 += __shfl_xor(Rt1, 16, 64);  Rt1 += __shfl_xor(Rt1, 32, 64);

    // folded top-MLP coefficients (channels 0..15 at c16; 16..19 at lane&3)
    const int om = c16;              // always < Ee
    const int ot = 16 + (lane & 3);  // always < Ee
    float uom = 0.0f, uot = 0.0f;
    #pragma unroll
    for (int p = 0; p < 10; ++p) {
        uom = fmaf(W2[p], W1[p * Ee + om], uom);
        uot = fmaf(W2[p], W1[p * Ee + ot], uot);
    }
    const float cfm0 = m0 * emb[zu0 * Ee + om];
    const float cfm1 = m1 * emb[zu1 * Ee + om];
    const float cft0 = m0 * emb[zu0 * Ee + ot];
    const float cft1 = m1 * emb[zu1 * Ee + ot];

    // epilogue: th = tanh(cf + m*(256 - 2R)); e = sum_o u[o]*th[o].
    // Tail terms appear 4x per 16-lane reduction group -> scale 0.25.
    float e = 0.0f;
    e = fmaf(tanhfast(cfm0 + m0 * (256.0f - 2.0f * Rm0)), uom, e);
    e = fmaf(tanhfast(cfm1 + m1 * (256.0f - 2.0f * Rm1)), uom, e);
    e = fmaf(tanhfast(cft0 + m0 * (256.0f - 2.0f * Rt0)), 0.25f * uot, e);
    e = fmaf(tanhfast(cft1 + m1 * (256.0f - 2.0f * Rt1)), 0.25f * uot, e);
    e += __shfl_xor(e, 1, 64);
    e += __shfl_xor(e, 2, 64);
    e += __shfl_xor(e, 4, 64);
    e += __shfl_xor(e, 8, 64);

    // block reduce: 4 waves -> one plain store (NO atomics)
    __shared__ float sE[4];
    if (lane == 0) sE[wave] = e;
    __syncthreads();
    if (tid == 0)
        part[blk] = sE[0] + sE[1] + sE[2] + sE[3];
}

// 64 blocks x 64 lanes: out[b] = sum of 32 block-partials + 256*C0
__global__ __launch_bounds__(64) void dtnn_reduce(
    const float* __restrict__ part,
    const float* __restrict__ b1, const float* __restrict__ W2,
    const float* __restrict__ b2, float* __restrict__ out)
{
    const int b = blockIdx.x;
    const int t = threadIdx.x;
    float v = (t < 32) ? part[b * 32 + t] : 0.0f;
    v += __shfl_xor(v, 1, 64);
    v += __shfl_xor(v, 2, 64);
    v += __shfl_xor(v, 4, 64);
    v += __shfl_xor(v, 8, 64);
    v += __shfl_xor(v, 16, 64);
    if (t == 0) {
        float c0 = b2[0];
        #pragma unroll
        for (int p = 0; p < 10; ++p) c0 = fmaf(W2[p], b1[p], c0);
        out[b] = v + __shfl(v, 32, 64) * 0.0f + 256.0f * c0 + __shfl_xor(v, 32, 64);
    }
}

extern "C" void kernel_launch(void* const* d_in, const int* in_sizes, int n_in,
                              void* d_out, int out_size, void* d_ws, size_t ws_size,
                              hipStream_t stream) {
    const int*   z    = (const int*)  d_in[0];
    const float* dist = (const float*)d_in[1];
    const float* emb  = (const float*)d_in[2];
    const float* Vw   = (const float*)d_in[3];
    const float* Vb   = (const float*)d_in[4];
    const float* W1   = (const float*)d_in[5];
    const float* b1   = (const float*)d_in[6];
    const float* W2   = (const float*)d_in[7];
    const float* b2   = (const float*)d_in[8];
    float* out = (float*)d_out;

    float* partP = (float*)d_ws;   // [NBLK]

    // 2 dispatches: fat main (2 rows/wave, self-contained) + tiny reduce
    dtnn_main<<<NBLK, 256, 0, stream>>>(z, dist, emb, Vw, Vb, W1, W2, partP);
    dtnn_reduce<<<Bsz, 64, 0, stream>>>(partP, b1, W2, b2, out);
}

// Round 4
// 110.614 us; speedup vs baseline: 1.1022x; 1.0261x over previous
//
#include <hip/hip_runtime.h>

#define Bsz 64
#define Nn  256
#define Ee  20   // atom embedding dim
#define Dd  25   // gaussian centers
#define NBLK 2048  // 2048 blocks x 4 waves x 2 rows = 16384 (b,i) rows

using short8  = __attribute__((ext_vector_type(8))) short;  // 8 bf16 (4 VGPRs)
using floatx4 = __attribute__((ext_vector_type(4))) float;  // 4 fp32 acc
using float2v = __attribute__((ext_vector_type(2))) float;  // pk-f32 pair

#if __has_builtin(__builtin_amdgcn_exp2f)
#define EXP2F(x) __builtin_amdgcn_exp2f(x)
#else
#define EXP2F(x) __expf(0.6931471805599453f * (x))
#endif
#if __has_builtin(__builtin_amdgcn_rcpf)
#define RCPF(x) __builtin_amdgcn_rcpf(x)
#else
#define RCPF(x) (1.0f / (x))
#endif

__device__ __forceinline__ short f2bf(float x) {            // RNE fp32->bf16
    unsigned u = __float_as_uint(x);
    unsigned r = (u + 0x7FFFu + ((u >> 16) & 1u)) >> 16;
    return (short)r;
}
__device__ __forceinline__ float bf2f(short h) {
    return __uint_as_float(((unsigned)(unsigned short)h) << 16);
}
__device__ __forceinline__ float tanhfast(float x) {
    float e = __expf(2.0f * x);
    return 1.0f - 2.0f / (e + 1.0f);
}
// pack two fp32 -> two bf16 in one VALU op (RNE). dst.lo=cvt(a), dst.hi=cvt(b)
__device__ __forceinline__ unsigned packbf(float a, float b) {
    unsigned r;
    asm("v_cvt_pk_bf16_f32 %0, %1, %2" : "=v"(r) : "v"(a), "v"(b));
    return r;
}
// packed fma on row-pairs
__device__ __forceinline__ float2v pkfma(float2v a, float2v b, float2v c) {
    return __builtin_elementwise_fma(a, b, c);
}

// Tail compaction: valid tail data = regs 0..3 at lanes c16<4.
// 3x update_dpp(row_shr:4m, bank_mask 1<<m) -> lane L holds element
// (jsub=4*(L>>4)+((L>>2)&3), o=16+(L&3)); bijective. Returns 2^x (no +1).
__device__ __forceinline__ float tailE(floatx4 p) {
    int r = __float_as_int(p[0]);
    r = __builtin_amdgcn_update_dpp(r, __float_as_int(p[1]), 0x114, 0xF, 0x2, false);
    r = __builtin_amdgcn_update_dpp(r, __float_as_int(p[2]), 0x118, 0xF, 0x4, false);
    r = __builtin_amdgcn_update_dpp(r, __float_as_int(p[3]), 0x11C, 0xF, 0x8, false);
    return EXP2F(__int_as_float(r));
}

// Main kernel. Each wave owns 2 rows (b,i0),(b,i0+1); 4 waves/block share b.
// Rows are PAIRED through the whole scalar path via packed-f32 (v_pk_*_f32):
// LDS holds interleaved {row0[j],row1[j]} so ds_read_b64 yields the pair.
__global__ __launch_bounds__(256, 4) void dtnn_main(
    const int*   __restrict__ z,     // [B,N]
    const float* __restrict__ dist,  // [B,N,N]
    const float* __restrict__ emb,   // [N,E]
    const float* __restrict__ Vw,    // [E,45]
    const float* __restrict__ Vb,    // [E]
    const float* __restrict__ W1,    // [10,E]
    const float* __restrict__ W2,    // [1,10]
    float*       __restrict__ part)  // [NBLK]
{
    const int tid  = threadIdx.x;
    const int lane = tid & 63;
    const int wave = tid >> 6;
    const int blk  = blockIdx.x;
    const int b    = blk >> 5;                       // 32 blocks per batch
    const int i0   = ((blk & 31) << 3) | (wave << 1);// rows i0, i0+1

    const int c16  = lane & 15;
    const int quad = lane >> 4;
    const int k0   = quad * 8;
    const float Kc = 2.8853900817779268f;            // 2*log2(e)
    const float T04 = 1.1541560327111707f;           // 0.4*Kc

    // wave-private LDS, interleaved row pair: sDw[2*j] = row0[j], [2*j+1] = row1[j]
    __shared__ float sD[4][2 * 256];
    float* sDw = sD[wave];

    // 8 coalesced row loads issued FIRST; latency hides under weight prologue
    const float* dr0 = dist + ((size_t)b * Nn + i0) * Nn;
    const float a0r = dr0[lane],        a1r = dr0[lane + 64];
    const float a2r = dr0[lane + 128],  a3r = dr0[lane + 192];
    const float b0r = dr0[Nn + lane],       b1r = dr0[Nn + lane + 64];
    const float b2r = dr0[Nn + lane + 128], b3r = dr0[Nn + lane + 192];

    const int zi0 = z[b * Nn + i0];
    const int zi1 = z[b * Nn + i0 + 1];
    const int zu0 = __builtin_amdgcn_readfirstlane(zi0);  // wave-uniform
    const int zu1 = __builtin_amdgcn_readfirstlane(zi1);
    const float m0 = (zu0 != 0) ? 1.0f : 0.0f;
    const float m1 = (zu1 != 0) ? 1.0f : 0.0f;

    // Gaussian step constants c_jj = e^{-0.08 jj^2}, folded into the weights.
    const float cj[8] = {1.0f, 0.9231163463866358f, 0.7261490370736909f,
                         0.48675225595997157f, 0.2780373004531941f,
                         0.1353352832366127f, 0.05613476283303940f,
                         0.019841459768337877f};

    // weight fragments (divergent gathers; L1-hot) + per-row bias
    short8 whiK[2], wloK[2];
    floatx4 bias0[2], bias1[2];
    #pragma unroll
    for (int nt = 0; nt < 2; ++nt) {
        const int o = nt * 16 + c16;
        const bool valid = (o < Ee);
        const int oc = valid ? o : 0;                 // clamp vs OOB speculation
        #pragma unroll
        for (int jj = 0; jj < 8; ++jj) {
            const int k = k0 + jj;
            const float v = (valid && k < Dd)
                          ? Kc * cj[jj] * Vw[oc * 45 + 20 + k] : 0.0f;
            const short h = f2bf(v);
            whiK[nt][jj] = h;
            wloK[nt][jj] = f2bf(v - bf2f(h));
        }
        // A[o] = Kc*(Vb[o] + m * Vw[o,:20].emb[z])
        float dot0 = 0.0f, dot1 = 0.0f;
        #pragma unroll
        for (int f = 0; f < Ee; ++f) {
            const float w = valid ? Vw[oc * 45 + f] : 0.0f;
            dot0 = fmaf(w, emb[zu0 * Ee + f], dot0);   // emb: s_loads (uniform)
            dot1 = fmaf(w, emb[zu1 * Ee + f], dot1);
        }
        const float vb = valid ? Vb[oc] : 0.0f;
        const float A0 = Kc * (vb + m0 * dot0);
        const float A1 = Kc * (vb + m1 * dot1);
        bias0[nt] = (floatx4){A0, A0, A0, A0};
        bias1[nt] = (floatx4){A1, A1, A1, A1};
    }

    // stage rows into wave-private LDS as interleaved pairs (4x ds_write_b64)
    *(float2v*)&sDw[2 * lane]         = (float2v){a0r, b0r};
    *(float2v*)&sDw[2 * (lane + 64)]  = (float2v){a1r, b1r};
    *(float2v*)&sDw[2 * (lane + 128)] = (float2v){a2r, b2r};
    *(float2v*)&sDw[2 * (lane + 192)] = (float2v){a3r, b3r};

    // ---- main loop: 16 j-tiles; rows packed as float2 {row0,row1}
    const float mu0 = 0.2f * (float)k0;
    float2v Rm2 = {0.0f, 0.0f};     // main channels (c16), per-row in .x/.y
    float2v Rt2 = {0.0f, 0.0f};     // tail channels (16+(lane&3))

    #pragma unroll
    for (int t = 0; t < 16; ++t) {
        // one ds_read_b64: {d_row0, d_row1}, 4-lane same-address broadcast
        const float2v d2 = *(const float2v*)&sDw[2 * (16 * t + c16)];

        // gaussian args (packed): g0 = 2^(-Kc u^2), tp = 2^(0.4*Kc u)
        const float2v u2 = d2 - mu0;
        const float2v aG = (u2 * (-Kc)) * u2;
        const float2v aT = u2 * T04;
        const float2v g0 = {EXP2F(aG.x), EXP2F(aG.y)};
        const float2v tp = {EXP2F(aT.x), EXP2F(aT.y)};

        // packed serial power ladder: x_k = g0 * tp^k (c_k folded into weights)
        const float2v x1 = g0 * tp;
        const float2v x2 = x1 * tp;
        const float2v x3 = x2 * tp;
        const float2v x4 = x3 * tp;
        const float2v x5 = x4 * tp;
        const float2v x6 = x5 * tp;
        const float2v x7 = x6 * tp;

        short8 GA, GB;
        {
            union { short8 s; unsigned u4[4]; } U;
            U.u4[0] = packbf(g0.x, x1.x); U.u4[1] = packbf(x2.x, x3.x);
            U.u4[2] = packbf(x4.x, x5.x); U.u4[3] = packbf(x6.x, x7.x);
            GA = U.s;
            U.u4[0] = packbf(g0.y, x1.y); U.u4[1] = packbf(x2.y, x3.y);
            U.u4[2] = packbf(x4.y, x5.y); U.u4[3] = packbf(x6.y, x7.y);
            GB = U.s;
        }

        // 8 MFMAs (2 rows x 2 ntiles x hi/lo), bias as C operand
        floatx4 p00 = __builtin_amdgcn_mfma_f32_16x16x32_bf16(GA, whiK[0], bias0[0], 0, 0, 0);
        p00 = __builtin_amdgcn_mfma_f32_16x16x32_bf16(GA, wloK[0], p00, 0, 0, 0);
        floatx4 p01 = __builtin_amdgcn_mfma_f32_16x16x32_bf16(GA, whiK[1], bias0[1], 0, 0, 0);
        p01 = __builtin_amdgcn_mfma_f32_16x16x32_bf16(GA, wloK[1], p01, 0, 0, 0);
        floatx4 p10 = __builtin_amdgcn_mfma_f32_16x16x32_bf16(GB, whiK[0], bias1[0], 0, 0, 0);
        p10 = __builtin_amdgcn_mfma_f32_16x16x32_bf16(GB, wloK[0], p10, 0, 0, 0);
        floatx4 p11 = __builtin_amdgcn_mfma_f32_16x16x32_bf16(GB, whiK[1], bias1[1], 0, 0, 0);
        p11 = __builtin_amdgcn_mfma_f32_16x16x32_bf16(GB, wloK[1], p11, 0, 0, 0);

        // sigma combine, packed across rows: A_i = 2^p_i + 1
        float2v A0 = {EXP2F(p00[0]), EXP2F(p10[0])};
        float2v A1 = {EXP2F(p00[1]), EXP2F(p10[1])};
        float2v A2 = {EXP2F(p00[2]), EXP2F(p10[2])};
        float2v A3 = {EXP2F(p00[3]), EXP2F(p10[3])};
        A0 += 1.0f; A1 += 1.0f; A2 += 1.0f; A3 += 1.0f;
        const float2v q01 = A0 * A1, q23 = A2 * A3;
        const float2v n4 = pkfma(q01, A2 + A3, q23 * (A0 + A1));
        const float2v d4 = q01 * q23;

        // tail channel (DPP-compacted, 1 exp per row)
        float2v At2 = {tailE(p01), tailE(p11)};
        At2 += 1.0f;

        // one reciprocal for both rows (magnitude-safe; |pre| small)
        const float2v Da = d4 * At2;
        const float inv = RCPF(Da.x * Da.y);
        const float2v inv2 = {inv * Da.y, inv * Da.x};   // {1/Da.x, 1/Da.y}
        Rm2 = pkfma(n4 * At2, inv2, Rm2);   // += sum 1/A_i  (4 main sigmas)
        Rt2 = pkfma(d4, inv2, Rt2);         // += 1/At       (tail sigma)
    }

    // unpack rows, then reduce as before
    float Rm0 = Rm2.x, Rm1 = Rm2.y, Rt0 = Rt2.x, Rt1 = Rt2.y;
    Rm0 += __shfl_xor(Rm0, 16, 64);  Rm0 += __shfl_xor(Rm0, 32, 64);
    Rm1 += __shfl_xor(Rm1, 16, 64);  Rm1 += __shfl_xor(Rm1, 32, 64);
    Rt0 += __shfl_xor(Rt0, 4, 64);   Rt0 += __shfl_xor(Rt0, 8, 64);
    Rt0 += __shfl_xor(Rt0, 16, 64);  Rt0 += __shfl_xor(Rt0, 32, 64);
    Rt1 += __shfl_xor(Rt1, 4, 64);   Rt1 += __shfl_xor(Rt1, 8, 64);
    Rt1 += __shfl_xor(Rt1, 16, 64);  Rt1 += __shfl_xor(Rt1, 32, 64);

    // folded top-MLP coefficients (channels 0..15 at c16; 16..19 at lane&3)
    const int om = c16;              // always < Ee
    const int ot = 16 + (lane & 3);  // always < Ee
    float uom = 0.0f, uot = 0.0f;
    #pragma unroll
    for (int p = 0; p < 10; ++p) {
        uom = fmaf(W2[p], W1[p * Ee + om], uom);
        uot = fmaf(W2[p], W1[p * Ee + ot], uot);
    }
    const float cfm0 = m0 * emb[zu0 * Ee + om];
    const float cfm1 = m1 * emb[zu1 * Ee + om];
    const float cft0 = m0 * emb[zu0 * Ee + ot];
    const float cft1 = m1 * emb[zu1 * Ee + ot];

    // epilogue: th = tanh(cf + m*(256 - 2R)); e = sum_o u[o]*th[o].
    // Tail terms appear 4x per 16-lane reduction group -> scale 0.25.
    float e = 0.0f;
    e = fmaf(tanhfast(cfm0 + m0 * (256.0f - 2.0f * Rm0)), uom, e);
    e = fmaf(tanhfast(cfm1 + m1 * (256.0f - 2.0f * Rm1)), uom, e);
    e = fmaf(tanhfast(cft0 + m0 * (256.0f - 2.0f * Rt0)), 0.25f * uot, e);
    e = fmaf(tanhfast(cft1 + m1 * (256.0f - 2.0f * Rt1)), 0.25f * uot, e);
    e += __shfl_xor(e, 1, 64);
    e += __shfl_xor(e, 2, 64);
    e += __shfl_xor(e, 4, 64);
    e += __shfl_xor(e, 8, 64);

    // block reduce: 4 waves -> one plain store (NO atomics)
    __shared__ float sE[4];
    if (lane == 0) sE[wave] = e;
    __syncthreads();
    if (tid == 0)
        part[blk] = sE[0] + sE[1] + sE[2] + sE[3];
}

// 64 blocks x 64 lanes: out[b] = sum of 32 block-partials + 256*C0
__global__ __launch_bounds__(64) void dtnn_reduce(
    const float* __restrict__ part,
    const float* __restrict__ b1, const float* __restrict__ W2,
    const float* __restrict__ b2, float* __restrict__ out)
{
    const int b = blockIdx.x;
    const int t = threadIdx.x;
    float v = (t < 32) ? part[b * 32 + t] : 0.0f;
    v += __shfl_xor(v, 1, 64);
    v += __shfl_xor(v, 2, 64);
    v += __shfl_xor(v, 4, 64);
    v += __shfl_xor(v, 8, 64);
    v += __shfl_xor(v, 16, 64);
    if (t == 0) {
        float c0 = b2[0];
        #pragma unroll
        for (int p = 0; p < 10; ++p) c0 = fmaf(W2[p], b1[p], c0);
        out[b] = v + __shfl(v, 32, 64) * 0.0f + 256.0f * c0 + __shfl_xor(v, 32, 64);
    }
}

extern "C" void kernel_launch(void* const* d_in, const int* in_sizes, int n_in,
                              void* d_out, int out_size, void* d_ws, size_t ws_size,
                              hipStream_t stream) {
    const int*   z    = (const int*)  d_in[0];
    const float* dist = (const float*)d_in[1];
    const float* emb  = (const float*)d_in[2];
    const float* Vw   = (const float*)d_in[3];
    const float* Vb   = (const float*)d_in[4];
    const float* W1   = (const float*)d_in[5];
    const float* b1   = (const float*)d_in[6];
    const float* W2   = (const float*)d_in[7];
    const float* b2   = (const float*)d_in[8];
    float* out = (float*)d_out;

    float* partP = (float*)d_ws;   // [NBLK]

    // 2 dispatches: fat main (2 rows/wave, self-contained) + tiny reduce
    dtnn_main<<<NBLK, 256, 0, stream>>>(z, dist, emb, Vw, Vb, W1, W2, partP);
    dtnn_reduce<<<Bsz, 64, 0, stream>>>(partP, b1, W2, b2, out);
}